// Round 4
// baseline (75.318 us; speedup 1.0000x reference)
//
#include <hip/hip_runtime.h>

#define DENSE 2048
#define BATCH 64
#define MAXS  1024
#define NSPLIT 8               // k-splits in spmm
#define PART_OFF (1 << 20)     // byte offset of partials region in ws (Cbf uses first 256 KB)

typedef __attribute__((ext_vector_type(8))) __bf16 bf16x8;
typedef __attribute__((ext_vector_type(4))) float f32x4;

// ws layout: Cbf[b][k] (bf16 counts) stored in MFMA A-fragment order so spmm's
// A-frag load is one coalesced global_load_dwordx4 per lane:
//   lane = (b&15) | (((k>>3)&3)<<4) holds C[b = mt*16 + (lane&15)][k = ks*32 + (lane>>4)*8 + i]
// == A[m=lane&15][k=(lane>>4)*8+i] for mfma_f32_16x16x32_bf16 (verified round 2, absmax 1.0).

__global__ __launch_bounds__(256) void hist_kernel(const int* __restrict__ ids,
                                                   const int* __restrict__ ns,
                                                   __bf16* __restrict__ Cbf) {
    __shared__ int cnt[DENSE];
    const int b = blockIdx.x;
    const int tid = threadIdx.x;
    #pragma unroll
    for (int k = tid; k < DENSE; k += 256) cnt[k] = 0;
    __syncthreads();
    const int n = ns[b];
    for (int i = tid; i < n; i += 256) {
        atomicAdd(&cnt[ids[b * MAXS + i]], 1);
    }
    __syncthreads();
    const int mt = b >> 4;
    const int bl = b & 15;
    #pragma unroll
    for (int k = tid; k < DENSE; k += 256) {
        const int lane = bl | (((k >> 3) & 3) << 4);
        const size_t off = (size_t)(((k >> 5) * 4 + mt) * 64 + lane) * 8 + (k & 7);
        Cbf[off] = (__bf16)(float)cnt[k];
    }
}

// spmm: partial[b][j] = sum_{k in split} C[b][k] * W[j][k] via bf16 MFMA 16x16x32.
// grid (128 j-tiles of 16, 8 k-splits of 256); 4 waves/block, 2 k-steps/wave.
// No atomics: each (jt,split) block stores its 64x16 partial tile to ws; a
// third kernel sums the 8 splits. launch_bounds(256,5): ~5 blocks/CU, 20 waves/CU.
__global__ __launch_bounds__(256, 5) void spmm_kernel(const float* __restrict__ W,
                                                      const __bf16* __restrict__ Cbf,
                                                      float* __restrict__ pws) {
    const int tid  = threadIdx.x;
    const int lane = tid & 63;
    const int wv   = tid >> 6;          // 0..3
    const int j0   = blockIdx.x * 16;   // j tile
    const int ks4  = blockIdx.y;        // 0..7 k split

    const int ln = lane & 15;           // j index within tile (B-frag n)
    const int lq = lane >> 4;           // k quad 0..3

    const int step0 = ks4 * 8 + wv * 2;
    const float* wrow = W + (size_t)(j0 + ln) * DENSE;

    // issue all 4 W loads + 8 A loads (compiler batches; plain cached loads —
    // NT regressed in R3: w0/w1 pairs rely on L2 line retention)
    f32x4 w0[2], w1[2];
    #pragma unroll
    for (int s = 0; s < 2; ++s) {
        const int kbase = (step0 + s) * 32 + lq * 8;
        w0[s] = *(const f32x4*)(wrow + kbase);
        w1[s] = *(const f32x4*)(wrow + kbase + 4);
    }
    bf16x8 afr[2][4];
    #pragma unroll
    for (int s = 0; s < 2; ++s) {
        #pragma unroll
        for (int mt = 0; mt < 4; ++mt) {
            afr[s][mt] = *(const bf16x8*)(Cbf + ((size_t)((step0 + s) * 4 + mt) * 64 + lane) * 8);
        }
    }

    bf16x8 wb[2];
    #pragma unroll
    for (int s = 0; s < 2; ++s) {
        #pragma unroll
        for (int i = 0; i < 4; ++i) {
            wb[s][i]     = (__bf16)w0[s][i];
            wb[s][i + 4] = (__bf16)w1[s][i];
        }
    }

    f32x4 acc[4];
    #pragma unroll
    for (int mt = 0; mt < 4; ++mt) acc[mt] = (f32x4)0.0f;
    #pragma unroll
    for (int s = 0; s < 2; ++s) {
        #pragma unroll
        for (int mt = 0; mt < 4; ++mt) {
            acc[mt] = __builtin_amdgcn_mfma_f32_16x16x32_bf16(afr[s][mt], wb[s], acc[mt], 0, 0, 0);
        }
    }

    // cross-wave LDS reduction, conflict-free layout P[wv][mt][r][lane]
    __shared__ float P[4][4][4][64];    // 16 KB
    #pragma unroll
    for (int mt = 0; mt < 4; ++mt) {
        #pragma unroll
        for (int r = 0; r < 4; ++r) {
            P[wv][mt][r][lane] = acc[mt][r];
        }
    }
    __syncthreads();

    // thread t -> (jloc = t&15 fastest for coalesced stores, bpart = t>>4)
    const int jloc  = tid & 15;
    const int bpart = tid >> 4;                       // 0..15
    const int lsrc  = ((bpart >> 2) << 4) | jloc;     // source lane
    const int r     = bpart & 3;                      // source acc reg
    float* pd = pws + (size_t)ks4 * (BATCH * DENSE);
    #pragma unroll
    for (int mt = 0; mt < 4; ++mt) {
        const float v = P[0][mt][r][lsrc] + P[1][mt][r][lsrc]
                      + P[2][mt][r][lsrc] + P[3][mt][r][lsrc];
        pd[(size_t)(mt * 16 + bpart) * DENSE + j0 + jloc] = v;
    }
}

// reduce: out[i] = sum over 8 splits of pws[s][i], float4-vectorized.
__global__ __launch_bounds__(256) void reduce_kernel(const float* __restrict__ pws,
                                                     float* __restrict__ out) {
    const int t = blockIdx.x * 256 + threadIdx.x;     // 0..32767
    const size_t i = (size_t)t * 4;
    f32x4 a = *(const f32x4*)(pws + i);
    #pragma unroll
    for (int s = 1; s < NSPLIT; ++s) {
        const f32x4 v = *(const f32x4*)(pws + (size_t)s * (BATCH * DENSE) + i);
        a.x += v.x; a.y += v.y; a.z += v.z; a.w += v.w;
    }
    *(f32x4*)(out + i) = a;
}

extern "C" void kernel_launch(void* const* d_in, const int* in_sizes, int n_in,
                              void* d_out, int out_size, void* d_ws, size_t ws_size,
                              hipStream_t stream) {
    const int*   ids = (const int*)d_in[0];   // [64, 1024] int32
    const int*   ns  = (const int*)d_in[1];   // [64] int32
    const float* W   = (const float*)d_in[2]; // [2048, 2048] float32
    float*  out = (float*)d_out;              // [64, 2048] float32
    __bf16* Cbf = (__bf16*)d_ws;              // 64*2048 bf16 = 256 KB
    float*  pws = (float*)((char*)d_ws + PART_OFF); // 8 * 512 KB partials

    hipLaunchKernelGGL(hist_kernel, dim3(BATCH), dim3(256), 0, stream, ids, ns, Cbf);
    hipLaunchKernelGGL(spmm_kernel, dim3(128, NSPLIT), dim3(256), 0, stream, W, Cbf, pws);
    hipLaunchKernelGGL(reduce_kernel, dim3((BATCH * DENSE / 4) / 256), dim3(256), 0, stream, pws, out);
}